// Round 1
// baseline (1220.234 us; speedup 1.0000x reference)
//
#include <hip/hip_runtime.h>
#include <cstdint>
#include <cstddef>

// ---------------------------------------------------------------------------
// TWLayer: out = (x ⊗ input-core chain) · central · (output-core chain) + bias
// Plan:
//   K0: transpose-cast central -> Bt[D][C] bf16; build fused 40x40 core-pair
//       matrices (c2x, c2in, c2out, c2last) in ws.
//   K1: per (b,l) input sweep in LDS (fp32), 5 fused stages -> S bf16 [51200][1024]
//   K2: MFMA bf16 GEMM  U[(b,l,r)][D] = S · central  (m97-style 128x128 tile),
//       epilogue writes U bf16 in K3's 40-contiguous per-row layout.
//   K3: per (b,l) output sweep in LDS (fp32), trace folded into last stage,
//       atomicAdd into zeroed d_out, bias added once.
// Workspace: S 100MB + U 100MB + Bt 2MB + cores ~64KB  (~212 MB)
// ---------------------------------------------------------------------------

typedef __attribute__((ext_vector_type(8))) short short8;   // 8 x bf16 (4 VGPR)
typedef __attribute__((ext_vector_type(4))) float f32x4;

static __device__ __forceinline__ unsigned short f2bf(float f) {
  union { float f; unsigned int u; } v; v.f = f;
  unsigned int r = v.u + 0x7FFFu + ((v.u >> 16) & 1u);   // RNE
  return (unsigned short)(r >> 16);
}
static __device__ __forceinline__ float bf2f(unsigned short h) {
  union { unsigned int u; float f; } v; v.u = ((unsigned int)h) << 16;
  return v.f;
}

// ---------------- K0: prep (transpose central + fused core pairs) ----------
__global__ __launch_bounds__(256) void k0_prep(
    const float* __restrict__ ic, const float* __restrict__ oc,
    const float* __restrict__ cc, unsigned short* __restrict__ Bt,
    float* __restrict__ c2x, float* __restrict__ c2in,
    float* __restrict__ c2out, float* __restrict__ c2last) {
  const int t = threadIdx.x;
  const int bx = blockIdx.x;
  if (bx < 1024) {
    // 32x32 tiled transpose-cast: Bt[D][C] = bf16(cc[C][D])
    __shared__ float tile[32][33];
    const int bi = bx >> 5, bj = bx & 31;
    const int tr = t >> 5, tc = t & 31;
    #pragma unroll
    for (int k = 0; k < 4; ++k) {
      int r = tr + k * 8;
      tile[r][tc] = cc[(size_t)(bi * 32 + r) * 1024 + bj * 32 + tc];
    }
    __syncthreads();
    #pragma unroll
    for (int k = 0; k < 4; ++k) {
      int r = tr + k * 8;
      Bt[(size_t)(bj * 32 + r) * 1024 + bi * 32 + tc] = f2bf(tile[tc][r]);
    }
  } else {
    // fused core-pair matrices. core layout: [i][l/r][p][c|d][s] (10,10,2,2,10)
    // c2x[l][pp][cc2*10+s] = sum_r ic0[l,p1,c1,r]*ic1[r,p2,c2,s]
    for (int idx = t; idx < 1600; idx += 256) {
      int l = idx / 160, rem = idx - l * 160, pp = rem / 40, n = rem - pp * 40;
      int p1 = pp >> 1, p2 = pp & 1, c12 = n / 10, s = n - c12 * 10;
      int c1 = c12 >> 1, c2v = c12 & 1;
      float a = 0.f;
      for (int r1 = 0; r1 < 10; ++r1)
        a += ic[l * 40 + p1 * 20 + c1 * 10 + r1] *
             ic[400 + r1 * 40 + p2 * 20 + c2v * 10 + s];
      c2x[idx] = a;
    }
    // c2in[st][k=r*4+p1p2][n=dd*10+s] : cores (2,3),(4,5),(6,7),(8,9)
    for (int idx = t; idx < 6400; idx += 256) {
      int st = idx / 1600, rem = idx - st * 1600, k = rem / 40, n = rem - k * 40;
      int r = k >> 2, p1 = (k >> 1) & 1, p2 = k & 1;
      int dd = n / 10, s = n - dd * 10, d1 = dd >> 1, d2 = dd & 1;
      const float* A = ic + (2 * st + 2) * 400;
      const float* B = ic + (2 * st + 3) * 400;
      float a = 0.f;
      for (int tt = 0; tt < 10; ++tt)
        a += A[r * 40 + p1 * 20 + d1 * 10 + tt] *
             B[tt * 40 + p2 * 20 + d2 * 10 + s];
      c2in[idx] = a;
    }
    // c2out[st][k=r*4+dd][n=pp*10+s] : cores (0,1),(2,3),(4,5),(6,7)
    for (int idx = t; idx < 6400; idx += 256) {
      int st = idx / 1600, rem = idx - st * 1600, k = rem / 40, n = rem - k * 40;
      int r = k >> 2, d1 = (k >> 1) & 1, d2 = k & 1;
      int pp = n / 10, s = n - pp * 10, p1 = pp >> 1, p2 = pp & 1;
      const float* A = oc + (2 * st) * 400;
      const float* B = oc + (2 * st + 1) * 400;
      float a = 0.f;
      for (int tt = 0; tt < 10; ++tt)
        a += A[r * 40 + p1 * 20 + d1 * 10 + tt] *
             B[tt * 40 + p2 * 20 + d2 * 10 + s];
      c2out[idx] = a;
    }
    // c2last[l][k=r*4+dd][pp] : cores (8,9) with trace s10 = l folded in
    for (int idx = t; idx < 1600; idx += 256) {
      int l = idx / 160, rem = idx - l * 160, k = rem >> 2, pp = rem & 3;
      int r = k >> 2, d1 = (k >> 1) & 1, d2 = k & 1;
      int p1 = pp >> 1, p2 = pp & 1;
      float a = 0.f;
      for (int tt = 0; tt < 10; ++tt)
        a += oc[8 * 400 + r * 40 + p1 * 20 + d1 * 10 + tt] *
             oc[9 * 400 + tt * 40 + p2 * 20 + d2 * 10 + l];
      c2last[idx] = a;
    }
  }
}

// ---------------- shared sweep helpers -------------------------------------
// LDS state: 256 rows x 40 words; row = x*(Q/4)+q; chunk r (10 x 16B, rotated
// by row%10 to spread banks), word = 2 soon-to-be-consumed bits.
__device__ __forceinline__ void read_state(const float* st, float inv[40],
                                           int t, int rot) {
  #pragma unroll
  for (int r = 0; r < 10; ++r) {
    int pos = r + rot; if (pos >= 10) pos -= 10;
    const float4 v = *(const float4*)&st[t * 40 + pos * 4];
    inv[r * 4 + 0] = v.x; inv[r * 4 + 1] = v.y;
    inv[r * 4 + 2] = v.z; inv[r * 4 + 3] = v.w;
  }
}
__device__ __forceinline__ void write_state(float* st, const float outv[40],
                                            int t, int sh0) {
  int x = t >> sh0;
  int q3 = t & ((1 << sh0) - 1);
  int shn = sh0 - 2;
  int Qn = 1 << shn;
  int ppn = q3 >> shn;
  int q4 = q3 & (Qn - 1);
  #pragma unroll
  for (int g = 0; g < 4; ++g) {
    int row = (4 * x + g) * Qn + q4;
    int rr = row % 10;
    int base = row * 40 + ppn;
    #pragma unroll
    for (int s = 0; s < 10; ++s) {
      int pos = s + rr; if (pos >= 10) pos -= 10;
      st[base + pos * 4] = outv[g * 10 + s];
    }
  }
}
// 1-row 40x40 stage; C2 is wave-uniform -> s_load + SGPR-operand v_fmac
__device__ __forceinline__ void stage40(const float* __restrict__ C2,
                                        const float inv[40], float outv[40]) {
  #pragma unroll
  for (int n = 0; n < 40; ++n) outv[n] = 0.f;
  #pragma unroll
  for (int k = 0; k < 40; ++k) {
    float iv = inv[k];
    #pragma unroll
    for (int n = 0; n < 40; ++n)
      outv[n] = fmaf(iv, C2[k * 40 + n], outv[n]);
  }
}

// ---------------- K1: input sweep ------------------------------------------
__global__ __launch_bounds__(256) void k1_insweep(
    const float* __restrict__ x, const float* __restrict__ c2x,
    const float* __restrict__ c2in, unsigned short* __restrict__ S) {
  __shared__ float st[10240];
  const int bx = blockIdx.x;            // 5120 = b*10 + l
  const int b = bx / 10, l = bx - b * 10;
  const int t = threadIdx.x;
  const int rot = t % 10;
  float outv[40];
  {  // stage X: absorb x bits (p1,p2) through cores 0,1
    const float* xb = x + (size_t)b * 1024;
    float xv[4];
    #pragma unroll
    for (int pp = 0; pp < 4; ++pp) xv[pp] = xb[pp * 256 + t];
    const float* C2 = c2x + l * 160;
    #pragma unroll
    for (int n = 0; n < 40; ++n) outv[n] = 0.f;
    #pragma unroll
    for (int pp = 0; pp < 4; ++pp) {
      float iv = xv[pp];
      #pragma unroll
      for (int n = 0; n < 40; ++n)
        outv[n] = fmaf(iv, C2[pp * 40 + n], outv[n]);
    }
  }
  write_state(st, outv, t, 8);
  __syncthreads();
  #pragma unroll 1
  for (int stg = 0; stg < 4; ++stg) {   // core pairs (2,3)..(8,9)
    float inv[40];
    read_state(st, inv, t, rot);
    stage40(c2in + stg * 1600, inv, outv);
    if (stg < 3) {
      __syncthreads();                  // all reads done before overwrite
      write_state(st, outv, t, 6 - 2 * stg);
      __syncthreads();
    }
  }
  // final state: row t = C-high bits c1..c8; outv[dd*10+s] -> col 4t+dd, A-row s
  const size_t blrow = (size_t)(b * 10 + l) * 10;
  #pragma unroll
  for (int s = 0; s < 10; ++s) {
    ushort4 pk;
    pk.x = f2bf(outv[s]);      pk.y = f2bf(outv[10 + s]);
    pk.z = f2bf(outv[20 + s]); pk.w = f2bf(outv[30 + s]);
    *(ushort4*)&S[(blrow + s) * 1024 + 4 * t] = pk;
  }
}

// ---------------- K2: bf16 MFMA GEMM  (M=51200, N=1024, K=1024) ------------
__global__ __launch_bounds__(256) void k2_gemm(
    const unsigned short* __restrict__ A,   // S   [51200][1024] bf16
    const unsigned short* __restrict__ B,   // Bt  [1024][1024]  bf16 (n-major)
    unsigned short* __restrict__ U) {       // U'  [5120][256][10][4] bf16
  __shared__ __align__(16) unsigned short Atile[128 * 32];
  __shared__ __align__(16) unsigned short Btile[128 * 32];
  const int t = threadIdx.x;
  const int bx = blockIdx.x;
  const int bn = bx & 7, bm = bx >> 3;
  const int wave = t >> 6, lane = t & 63;
  const int wm = wave & 1, wn = wave >> 1;

  f32x4 acc[4][4];
  #pragma unroll
  for (int i = 0; i < 4; ++i)
    #pragma unroll
    for (int j = 0; j < 4; ++j) acc[i][j] = (f32x4){0.f, 0.f, 0.f, 0.f};

  const int arow = t >> 2;                 // 0..63 (second issue: +64)
  const int achk = t & 3;
  const unsigned short* Ag = A + (size_t)(bm * 128 + arow) * 1024 + achk * 8;
  const unsigned short* Bg = B + (size_t)(bn * 128 + arow) * 1024 + achk * 8;
  char* ldsA = (char*)Atile + wave * 1024; // wave-uniform LDS base (+ lane*16 by HW)
  char* ldsB = (char*)Btile + wave * 1024;

  for (int k0 = 0; k0 < 1024; k0 += 32) {
    __builtin_amdgcn_global_load_lds(
        (const __attribute__((address_space(1))) void*)(Ag + k0),
        (__attribute__((address_space(3))) void*)ldsA, 16, 0, 0);
    __builtin_amdgcn_global_load_lds(
        (const __attribute__((address_space(1))) void*)(Ag + 64 * 1024 + k0),
        (__attribute__((address_space(3))) void*)(ldsA + 4096), 16, 0, 0);
    __builtin_amdgcn_global_load_lds(
        (const __attribute__((address_space(1))) void*)(Bg + k0),
        (__attribute__((address_space(3))) void*)ldsB, 16, 0, 0);
    __builtin_amdgcn_global_load_lds(
        (const __attribute__((address_space(1))) void*)(Bg + 64 * 1024 + k0),
        (__attribute__((address_space(3))) void*)(ldsB + 4096), 16, 0, 0);
    __syncthreads();
    short8 af[4], bf[4];
    const int kq = (lane >> 4) * 8;
    #pragma unroll
    for (int mt = 0; mt < 4; ++mt)
      af[mt] = *(const short8*)&Atile[(wm * 64 + mt * 16 + (lane & 15)) * 32 + kq];
    #pragma unroll
    for (int nt = 0; nt < 4; ++nt)
      bf[nt] = *(const short8*)&Btile[(wn * 64 + nt * 16 + (lane & 15)) * 32 + kq];
    #pragma unroll
    for (int mt = 0; mt < 4; ++mt)
      #pragma unroll
      for (int nt = 0; nt < 4; ++nt)
        acc[mt][nt] = __builtin_amdgcn_mfma_f32_16x16x32_bf16(
            af[mt], bf[nt], acc[mt][nt], 0, 0, 0);
    __syncthreads();
  }
  // epilogue: C/D layout col=lane&15, row=(lane>>4)*4+i; write U' layout
  const int col0 = bn * 128 + wn * 64 + (lane & 15);
  const int row0 = bm * 128 + wm * 64 + (lane >> 4) * 4;
  #pragma unroll
  for (int mt = 0; mt < 4; ++mt) {
    #pragma unroll
    for (int i = 0; i < 4; ++i) {
      int m = row0 + mt * 16 + i;
      int bl = m / 10;
      int r = m - bl * 10;
      size_t ub = (size_t)bl * 10240;
      #pragma unroll
      for (int nt = 0; nt < 4; ++nt) {
        int n = col0 + nt * 16;
        int dp = n >> 8, q3 = n & 255;
        U[ub + q3 * 40 + r * 4 + dp] = f2bf(acc[mt][nt][i]);
      }
    }
  }
}

// ---------------- K3: output sweep + trace + bias --------------------------
__global__ __launch_bounds__(256) void k3_outsweep(
    const unsigned short* __restrict__ U, const float* __restrict__ c2out,
    const float* __restrict__ c2last, const float* __restrict__ bias,
    float* __restrict__ out) {
  __shared__ float st[10240];
  const int bx = blockIdx.x;              // 1024 = b*2 + lhalf
  const int b = bx >> 1, lh = bx & 1;
  const int t = threadIdx.x;
  const int rot = t % 10;
  float acc[4] = {0.f, 0.f, 0.f, 0.f};
  #pragma unroll 1
  for (int li = 0; li < 5; ++li) {
    const int l = lh * 5 + li;
    float outv[40];
    #pragma unroll 1
    for (int stg = 0; stg < 4; ++stg) {   // core pairs (0,1)..(6,7)
      float inv[40];
      if (stg == 0) {                     // read U' straight from global
        const unsigned short* Ur = U + (size_t)(b * 10 + l) * 10240 + t * 40;
        #pragma unroll
        for (int j = 0; j < 10; ++j) {
          ushort4 v = *(const ushort4*)&Ur[j * 4];
          inv[j * 4 + 0] = bf2f(v.x); inv[j * 4 + 1] = bf2f(v.y);
          inv[j * 4 + 2] = bf2f(v.z); inv[j * 4 + 3] = bf2f(v.w);
        }
      } else {
        read_state(st, inv, t, rot);
      }
      stage40(c2out + stg * 1600, inv, outv);
      __syncthreads();                    // protects prior reads (incl. last O4)
      write_state(st, outv, t, 8 - 2 * stg);
      __syncthreads();
    }
    {  // last stage: cores (8,9) with trace folded; row t = P-high bits
      float inv[40];
      read_state(st, inv, t, rot);
      const float* CL = c2last + l * 160;
      #pragma unroll
      for (int k = 0; k < 40; ++k) {
        float iv = inv[k];
        #pragma unroll
        for (int p = 0; p < 4; ++p)
          acc[p] = fmaf(iv, CL[k * 4 + p], acc[p]);
      }
    }
  }
  if (lh == 0) {
    #pragma unroll
    for (int p = 0; p < 4; ++p) acc[p] += bias[4 * t + p];
  }
  #pragma unroll
  for (int p = 0; p < 4; ++p)
    atomicAdd(&out[(size_t)b * 1024 + 4 * t + p], acc[p]);
}

// ---------------- launch ----------------------------------------------------
extern "C" void kernel_launch(void* const* d_in, const int* in_sizes, int n_in,
                              void* d_out, int out_size, void* d_ws, size_t ws_size,
                              hipStream_t stream) {
  (void)in_sizes; (void)n_in; (void)ws_size;
  const float* x    = (const float*)d_in[0];
  const float* ic   = (const float*)d_in[1];
  const float* oc   = (const float*)d_in[2];
  const float* cc   = (const float*)d_in[3];
  const float* bias = (const float*)d_in[4];
  float* out = (float*)d_out;

  char* ws = (char*)d_ws;
  unsigned short* S      = (unsigned short*)(ws);              // 104857600 B
  unsigned short* U      = (unsigned short*)(ws + 104857600);  // 104857600 B
  unsigned short* Bt     = (unsigned short*)(ws + 209715200);  //   2097152 B
  float*          c2x    = (float*)(ws + 211812352);           //      6400 B
  float*          c2in   = (float*)(ws + 211818752);           //     25600 B
  float*          c2out  = (float*)(ws + 211844352);           //     25600 B
  float*          c2last = (float*)(ws + 211869952);           //      6400 B

  hipMemsetAsync(d_out, 0, (size_t)out_size * sizeof(float), stream);
  k0_prep<<<1025, 256, 0, stream>>>(ic, oc, cc, Bt, c2x, c2in, c2out, c2last);
  k1_insweep<<<5120, 256, 0, stream>>>(x, c2x, c2in, S);
  k2_gemm<<<3200, 256, 0, stream>>>(S, Bt, U);
  k3_outsweep<<<1024, 256, 0, stream>>>(U, c2out, c2last, bias, out);
}

// Round 2
// 693.611 us; speedup vs baseline: 1.7592x; 1.7592x over previous
//
#include <hip/hip_runtime.h>
#include <cstdint>
#include <cstddef>

// ---------------------------------------------------------------------------
// TWLayer: out = (x ⊗ input-core chain) · central · (output-core chain) + bias
//
// R1 rewrite of the sweeps: each fused 40x40 stage is a register-tiled GEMM.
//   wave w  <-> output col-slice dd = w  (the 2 bits that become new row bits)
//   lane l  <-> the 4 rows sharing (x, q4)  (pp = the 2 bits consumed next)
// => each thread's 40 outputs fill ONE new state row: 10x ds_write_b128.
//    A-reads: 40x ds_read_b128. B (core matrix): wave-uniform -> s_load/SGPR.
//    acc[4][10] register-resident (no dynamic indexing anywhere).
// LDS state: 256 rows x 44 floats (16B-aligned rows; 12*row mod 32 covers all
// 8 bank groups) + mod-10 chunk rotation by (row>>2)&3 -> <=2-way conflicts.
// S col-order permuted so K1's final stores are coalesced ushort4; Bt is built
// with the identical permutation (free in K0). U' layout [bl][chunk][row][sub]
// so K3 stage-0 global reads are coalesced ushort4.
// ---------------------------------------------------------------------------

typedef __attribute__((ext_vector_type(8))) short short8;   // 8 x bf16
typedef __attribute__((ext_vector_type(4))) float f32x4;

static __device__ __forceinline__ unsigned short f2bf(float f) {
  union { float f; unsigned int u; } v; v.f = f;
  unsigned int r = v.u + 0x7FFFu + ((v.u >> 16) & 1u);   // RNE
  return (unsigned short)(r >> 16);
}
static __device__ __forceinline__ float bf2f(unsigned short h) {
  union { unsigned int u; float f; } v; v.u = ((unsigned int)h) << 16;
  return v.f;
}

// LDS state addressing: row stride 44 floats, chunk rotation to spread banks.
static __device__ __forceinline__ int lds_off(int row, int c) {
  int pos = c + ((row >> 2) & 3);
  if (pos >= 10) pos -= 10;
  return row * 44 + pos * 4;
}

// One K-chunk of the 40x40 stage GEMM: A[pp_out] holds 4 k-values (sub=pp_in),
// B is wave-uniform (SGPR). 160 fmac.
static __device__ __forceinline__ void fma_chunk(
    const float* __restrict__ C2c, const f32x4 A[4], float acc[4][10]) {
  #pragma unroll
  for (int pi = 0; pi < 4; ++pi) {
    #pragma unroll
    for (int s = 0; s < 10; ++s) {
      const float bv = C2c[pi * 10 + s];
      acc[0][s] = fmaf(A[0][pi], bv, acc[0][s]);
      acc[1][s] = fmaf(A[1][pi], bv, acc[1][s]);
      acc[2][s] = fmaf(A[2][pi], bv, acc[2][s]);
      acc[3][s] = fmaf(A[3][pi], bv, acc[3][s]);
    }
  }
}

// ---------------- K0: prep ---------------------------------------------------
// Bt[d][c'] = bf16(cc[C(c')][d]) with C(c') = 4*(c'&255) + (c'>>8)
// (matches K1's S column order: c' = w*256 + staterow, staterow = 4l+pp).
// Core-pair matrices in wave-sliced layouts:
//   c2x   [L][w][pi][s]        (160/L)
//   c2in  [stg][c][w][pi][s]   (1600/stg)
//   c2out [stg][c][w][dd][s]   (1600/stg)
//   c2last[L][c][dd][p]        (160/L)
__global__ __launch_bounds__(256) void k0_prep(
    const float* __restrict__ ic, const float* __restrict__ oc,
    const float* __restrict__ cc, unsigned short* __restrict__ Bt,
    float* __restrict__ c2x, float* __restrict__ c2in,
    float* __restrict__ c2out, float* __restrict__ c2last) {
  const int t = threadIdx.x;
  const int bx = blockIdx.x;
  if (bx < 1024) {
    const int d = bx;
    const int base = 4 * ((4 * t) & 255) + (t >> 6);   // C for j=0; +4 per j
    ushort4 pk;
    pk.x = f2bf(cc[(size_t)(base + 0) * 1024 + d]);
    pk.y = f2bf(cc[(size_t)(base + 4) * 1024 + d]);
    pk.z = f2bf(cc[(size_t)(base + 8) * 1024 + d]);
    pk.w = f2bf(cc[(size_t)(base + 12) * 1024 + d]);
    *(ushort4*)&Bt[(size_t)d * 1024 + 4 * t] = pk;
  } else {
    // cores layout: [i][l/r][p][c|d][s] = (10,10,2,2,10)
    for (int idx = t; idx < 1600; idx += 256) {        // c2x
      int L = idx / 160, rem = idx - L * 160;
      int w = rem / 40, r2 = rem - w * 40;
      int pi = r2 / 10, s = r2 - pi * 10;
      int p1 = pi >> 1, p2 = pi & 1, c1 = w >> 1, c2v = w & 1;
      float a = 0.f;
      for (int r1 = 0; r1 < 10; ++r1)
        a += ic[L * 40 + p1 * 20 + c1 * 10 + r1] *
             ic[400 + r1 * 40 + p2 * 20 + c2v * 10 + s];
      c2x[idx] = a;
    }
    for (int idx = t; idx < 6400; idx += 256) {        // c2in
      int st = idx / 1600, rem = idx - st * 1600;
      int c = rem / 160, rem2 = rem - c * 160;
      int w = rem2 / 40, r3 = rem2 - w * 40;
      int pi = r3 / 10, s = r3 - pi * 10;
      int p1 = pi >> 1, p2 = pi & 1, d1 = w >> 1, d2 = w & 1;
      const float* A = ic + (2 * st + 2) * 400;
      const float* B = ic + (2 * st + 3) * 400;
      float a = 0.f;
      for (int tt = 0; tt < 10; ++tt)
        a += A[c * 40 + p1 * 20 + d1 * 10 + tt] *
             B[tt * 40 + p2 * 20 + d2 * 10 + s];
      c2in[idx] = a;
    }
    for (int idx = t; idx < 6400; idx += 256) {        // c2out
      int st = idx / 1600, rem = idx - st * 1600;
      int c = rem / 160, rem2 = rem - c * 160;
      int w = rem2 / 40, r3 = rem2 - w * 40;
      int dd = r3 / 10, s = r3 - dd * 10;
      int p1 = w >> 1, p2 = w & 1, d1 = dd >> 1, d2 = dd & 1;
      const float* A = oc + (2 * st) * 400;
      const float* B = oc + (2 * st + 1) * 400;
      float a = 0.f;
      for (int tt = 0; tt < 10; ++tt)
        a += A[c * 40 + p1 * 20 + d1 * 10 + tt] *
             B[tt * 40 + p2 * 20 + d2 * 10 + s];
      c2out[idx] = a;
    }
    for (int idx = t; idx < 1600; idx += 256) {        // c2last (trace folded)
      int L = idx / 160, rem = idx - L * 160;
      int c = rem / 16, dd = (rem >> 2) & 3, p = rem & 3;
      int d1 = dd >> 1, d2 = dd & 1, p1 = p >> 1, p2 = p & 1;
      float a = 0.f;
      for (int tt = 0; tt < 10; ++tt)
        a += oc[8 * 400 + c * 40 + p1 * 20 + d1 * 10 + tt] *
             oc[9 * 400 + tt * 40 + p2 * 20 + d2 * 10 + L];
      c2last[idx] = a;
    }
  }
}

// ---------------- K1: input sweep -------------------------------------------
__global__ __launch_bounds__(256) void k1_insweep(
    const float* __restrict__ x, const float* __restrict__ c2x,
    const float* __restrict__ c2in, unsigned short* __restrict__ S) {
  __shared__ __align__(16) float st[256 * 44];
  const int bx = blockIdx.x;                 // 5120 = b*10 + L
  const int b = bx / 10, L = bx - b * 10;
  const int t = threadIdx.x;
  const int l = t & 63;
  const int w = __builtin_amdgcn_readfirstlane(t >> 6);
  float acc[4][10];
  {  // stage X: absorb top 2 x-bit-pairs through cores 0,1 (K=4)
    const float* xb = x + (size_t)b * 1024;
    const float* C2 = c2x + L * 160 + w * 40;
    float xv[4][4];
    #pragma unroll
    for (int g = 0; g < 4; ++g)
      #pragma unroll
      for (int pi = 0; pi < 4; ++pi)
        xv[g][pi] = xb[pi * 256 + g * 64 + l];
    #pragma unroll
    for (int g = 0; g < 4; ++g)
      #pragma unroll
      for (int s = 0; s < 10; ++s) acc[g][s] = 0.f;
    #pragma unroll
    for (int pi = 0; pi < 4; ++pi)
      #pragma unroll
      for (int s = 0; s < 10; ++s) {
        const float bv = C2[pi * 10 + s];
        #pragma unroll
        for (int g = 0; g < 4; ++g)
          acc[g][s] = fmaf(xv[g][pi], bv, acc[g][s]);
      }
    const int rowNew = w * 64 + l;
    #pragma unroll
    for (int s = 0; s < 10; ++s) {
      f32x4 v = {acc[0][s], acc[1][s], acc[2][s], acc[3][s]};
      *(f32x4*)&st[lds_off(rowNew, s)] = v;
    }
  }
  __syncthreads();
  #pragma unroll 1
  for (int stg = 0; stg < 4; ++stg) {        // fused core pairs (2,3)..(8,9)
    const int sh0 = (stg < 2) ? (6 - 2 * stg) : 2;
    const int qb = sh0 - 2;
    const int xq = l >> qb;
    const int q4 = l & ((1 << qb) - 1);
    const int pstep = 1 << qb;
    const int r0 = (xq << sh0) + q4;
    const float* C2 = c2in + stg * 1600 + w * 40;
    #pragma unroll
    for (int g = 0; g < 4; ++g)
      #pragma unroll
      for (int s = 0; s < 10; ++s) acc[g][s] = 0.f;
    #pragma unroll 2
    for (int c = 0; c < 10; ++c) {
      f32x4 A[4];
      #pragma unroll
      for (int pp = 0; pp < 4; ++pp)
        A[pp] = *(const f32x4*)&st[lds_off(r0 + pp * pstep, c)];
      fma_chunk(C2 + c * 160, A, acc);
    }
    if (stg < 3) {
      __syncthreads();
      const int rowNew = ((4 * xq + w) << qb) + q4;
      #pragma unroll
      for (int s = 0; s < 10; ++s) {
        f32x4 v = {acc[0][s], acc[1][s], acc[2][s], acc[3][s]};
        *(f32x4*)&st[lds_off(rowNew, s)] = v;
      }
      __syncthreads();
    }
  }
  // S store: col' = w*256 + 4l + pp  (coalesced ushort4; Bt permuted to match)
  const size_t sb = ((size_t)(b * 10 + L) * 10) * 1024 + w * 256 + l * 4;
  #pragma unroll
  for (int s = 0; s < 10; ++s) {
    ushort4 pk;
    pk.x = f2bf(acc[0][s]); pk.y = f2bf(acc[1][s]);
    pk.z = f2bf(acc[2][s]); pk.w = f2bf(acc[3][s]);
    *(ushort4*)&S[sb + (size_t)s * 1024] = pk;
  }
}

// ---------------- K2: bf16 MFMA GEMM  (M=51200, N=1024, K=1024) ------------
__global__ __launch_bounds__(256) void k2_gemm(
    const unsigned short* __restrict__ A,   // S   [51200][1024] bf16
    const unsigned short* __restrict__ B,   // Bt  [1024][1024]  bf16 (n-major)
    unsigned short* __restrict__ U) {       // U'  [5120][10][256][4] bf16
  __shared__ __align__(16) unsigned short Atile[128 * 32];
  __shared__ __align__(16) unsigned short Btile[128 * 32];
  const int t = threadIdx.x;
  const int bx = blockIdx.x;
  const int bn = bx & 7, bm = bx >> 3;
  const int wave = t >> 6, lane = t & 63;
  const int wm = wave & 1, wn = wave >> 1;

  f32x4 acc[4][4];
  #pragma unroll
  for (int i = 0; i < 4; ++i)
    #pragma unroll
    for (int j = 0; j < 4; ++j) acc[i][j] = (f32x4){0.f, 0.f, 0.f, 0.f};

  const int arow = t >> 2;
  const int achk = t & 3;
  const unsigned short* Ag = A + (size_t)(bm * 128 + arow) * 1024 + achk * 8;
  const unsigned short* Bg = B + (size_t)(bn * 128 + arow) * 1024 + achk * 8;
  char* ldsA = (char*)Atile + wave * 1024;
  char* ldsB = (char*)Btile + wave * 1024;

  for (int k0 = 0; k0 < 1024; k0 += 32) {
    __builtin_amdgcn_global_load_lds(
        (const __attribute__((address_space(1))) void*)(Ag + k0),
        (__attribute__((address_space(3))) void*)ldsA, 16, 0, 0);
    __builtin_amdgcn_global_load_lds(
        (const __attribute__((address_space(1))) void*)(Ag + 64 * 1024 + k0),
        (__attribute__((address_space(3))) void*)(ldsA + 4096), 16, 0, 0);
    __builtin_amdgcn_global_load_lds(
        (const __attribute__((address_space(1))) void*)(Bg + k0),
        (__attribute__((address_space(3))) void*)ldsB, 16, 0, 0);
    __builtin_amdgcn_global_load_lds(
        (const __attribute__((address_space(1))) void*)(Bg + 64 * 1024 + k0),
        (__attribute__((address_space(3))) void*)(ldsB + 4096), 16, 0, 0);
    __syncthreads();
    short8 af[4], bf[4];
    const int kq = (lane >> 4) * 8;
    #pragma unroll
    for (int mt = 0; mt < 4; ++mt)
      af[mt] = *(const short8*)&Atile[(wm * 64 + mt * 16 + (lane & 15)) * 32 + kq];
    #pragma unroll
    for (int nt = 0; nt < 4; ++nt)
      bf[nt] = *(const short8*)&Btile[(wn * 64 + nt * 16 + (lane & 15)) * 32 + kq];
    #pragma unroll
    for (int mt = 0; mt < 4; ++mt)
      #pragma unroll
      for (int nt = 0; nt < 4; ++nt)
        acc[mt][nt] = __builtin_amdgcn_mfma_f32_16x16x32_bf16(
            af[mt], bf[nt], acc[mt][nt], 0, 0, 0);
    __syncthreads();
  }
  // epilogue: C/D layout col=lane&15, row=(lane>>4)*4+i; U'[bl][r][q3][dp]
  const int col0 = bn * 128 + wn * 64 + (lane & 15);
  const int row0 = bm * 128 + wm * 64 + (lane >> 4) * 4;
  #pragma unroll
  for (int mt = 0; mt < 4; ++mt) {
    #pragma unroll
    for (int i = 0; i < 4; ++i) {
      int m = row0 + mt * 16 + i;
      int bl = m / 10;
      int r = m - bl * 10;
      size_t ub = (size_t)bl * 10240 + (size_t)r * 1024;
      #pragma unroll
      for (int nt = 0; nt < 4; ++nt) {
        int n = col0 + nt * 16;
        U[ub + (n & 255) * 4 + (n >> 8)] = f2bf(acc[mt][nt][i]);
      }
    }
  }
}

// ---------------- K3: output sweep + trace + bias --------------------------
__global__ __launch_bounds__(256) void k3_outsweep(
    const unsigned short* __restrict__ U, const float* __restrict__ c2out,
    const float* __restrict__ c2last, const float* __restrict__ bias,
    float* __restrict__ out) {
  __shared__ __align__(16) float st[256 * 44];
  const int bx = blockIdx.x;                 // 5120 = b*10 + L
  const int b = bx / 10, L = bx - b * 10;
  const int t = threadIdx.x;
  const int l = t & 63;
  const int w = __builtin_amdgcn_readfirstlane(t >> 6);
  float acc[4][10];
  #pragma unroll 1
  for (int stg = 0; stg < 4; ++stg) {        // fused core pairs (0,1)..(6,7)
    const int sh0 = 8 - 2 * stg;
    const int qb = sh0 - 2;
    const int xq = l >> qb;
    const int q4 = l & ((1 << qb) - 1);
    const int pstep = 1 << qb;
    const int r0 = (xq << sh0) + q4;
    const float* C2 = c2out + stg * 1600 + w * 40;
    #pragma unroll
    for (int g = 0; g < 4; ++g)
      #pragma unroll
      for (int s = 0; s < 10; ++s) acc[g][s] = 0.f;
    if (stg == 0) {                          // U' straight from global
      const unsigned short* Ub = U + (size_t)(b * 10 + L) * 10240;
      #pragma unroll 2
      for (int c = 0; c < 10; ++c) {
        f32x4 A[4];
        #pragma unroll
        for (int pp = 0; pp < 4; ++pp) {
          ushort4 v = *(const ushort4*)&Ub[c * 1024 + (pp * 64 + l) * 4];
          A[pp] = (f32x4){bf2f(v.x), bf2f(v.y), bf2f(v.z), bf2f(v.w)};
        }
        fma_chunk(C2 + c * 160, A, acc);
      }
    } else {
      #pragma unroll 2
      for (int c = 0; c < 10; ++c) {
        f32x4 A[4];
        #pragma unroll
        for (int pp = 0; pp < 4; ++pp)
          A[pp] = *(const f32x4*)&st[lds_off(r0 + pp * pstep, c)];
        fma_chunk(C2 + c * 160, A, acc);
      }
    }
    __syncthreads();
    const int rowNew = ((4 * xq + w) << qb) + q4;
    #pragma unroll
    for (int s = 0; s < 10; ++s) {
      f32x4 v = {acc[0][s], acc[1][s], acc[2][s], acc[3][s]};
      *(f32x4*)&st[lds_off(rowNew, s)] = v;
    }
    __syncthreads();
  }
  // last stage: cores (8,9) with trace folded; one row (=t) per thread
  float accO[4] = {0.f, 0.f, 0.f, 0.f};
  const float* CL = c2last + L * 160;
  #pragma unroll 2
  for (int c = 0; c < 10; ++c) {
    const f32x4 A = *(const f32x4*)&st[lds_off(t, c)];
    #pragma unroll
    for (int dd = 0; dd < 4; ++dd)
      #pragma unroll
      for (int p = 0; p < 4; ++p)
        accO[p] = fmaf(A[dd], CL[c * 16 + dd * 4 + p], accO[p]);
  }
  if (L == 0) {
    #pragma unroll
    for (int p = 0; p < 4; ++p) accO[p] += bias[4 * t + p];
  }
  #pragma unroll
  for (int p = 0; p < 4; ++p)
    atomicAdd(&out[(size_t)b * 1024 + 4 * t + p], accO[p]);
}

// ---------------- launch ----------------------------------------------------
extern "C" void kernel_launch(void* const* d_in, const int* in_sizes, int n_in,
                              void* d_out, int out_size, void* d_ws, size_t ws_size,
                              hipStream_t stream) {
  (void)in_sizes; (void)n_in; (void)ws_size;
  const float* x    = (const float*)d_in[0];
  const float* ic   = (const float*)d_in[1];
  const float* oc   = (const float*)d_in[2];
  const float* cc   = (const float*)d_in[3];
  const float* bias = (const float*)d_in[4];
  float* out = (float*)d_out;

  char* ws = (char*)d_ws;
  unsigned short* S      = (unsigned short*)(ws);              // 104857600 B
  unsigned short* U      = (unsigned short*)(ws + 104857600);  // 104857600 B
  unsigned short* Bt     = (unsigned short*)(ws + 209715200);  //   2097152 B
  float*          c2x    = (float*)(ws + 211812352);           //      6400 B
  float*          c2in   = (float*)(ws + 211818752);           //     25600 B
  float*          c2out  = (float*)(ws + 211844352);           //     25600 B
  float*          c2last = (float*)(ws + 211869952);           //      6400 B

  hipMemsetAsync(d_out, 0, (size_t)out_size * sizeof(float), stream);
  k0_prep<<<1025, 256, 0, stream>>>(ic, oc, cc, Bt, c2x, c2in, c2out, c2last);
  k1_insweep<<<5120, 256, 0, stream>>>(x, c2x, c2in, S);
  k2_gemm<<<3200, 256, 0, stream>>>(S, Bt, U);
  k3_outsweep<<<5120, 256, 0, stream>>>(U, c2out, c2last, bias, out);
}

// Round 5
// 400.897 us; speedup vs baseline: 3.0438x; 1.7301x over previous
//
#include <hip/hip_runtime.h>
#include <cstdint>
#include <cstddef>

// ---------------------------------------------------------------------------
// TWLayer — all-MFMA pipeline (R4 = R3 + fixed LDS pad zeroing).
//   K0: Bt[delta][c''] (central, both sides permuted), c2x (stage-X f32),
//       per-stage MFMA B-fragment tables bf1/bf3/bf3l zero-padded to
//       K=64 / N=48 so A-side pad reads are annihilated (B=0).
//   K1: per (b,L): stage X on VALU (K=4), then 4 MFMA stages with LDS-resident
//       bf16 state; inter-stage bit permutation folded into D->LDS addressing.
//   K2: MFMA GEMM, M=1024 (central delta side) x N=51200 (S rows) x K=1024.
//   K3: mirror of K1 on the output chain; trace + bias + atomicAdd.
// R4 fix: zero_state previously stored uint2 (8 B) at 16-B stride, leaving
// uninitialized LDS gaps in the k-pad region -> MFMA 0*inf = NaN. Now a full
// 144-B wipe with true 16-B stores.
// ---------------------------------------------------------------------------

typedef __attribute__((ext_vector_type(8))) short short8;   // 8 x bf16
typedef __attribute__((ext_vector_type(4))) float f32x4;

static __device__ __forceinline__ unsigned short f2bf(float f) {
  union { float f; unsigned int u; } v; v.f = f;
  unsigned int r = v.u + 0x7FFFu + ((v.u >> 16) & 1u);   // RNE
  return (unsigned short)(r >> 16);
}
static __device__ __forceinline__ unsigned int pack2(float a, float b) {
  return (unsigned int)f2bf(a) | ((unsigned int)f2bf(b) << 16);
}

// ---- stage-permutation row maps (element-verified; g always = m&3) --------
static __device__ __forceinline__ int shuf_in(int stg, int u, int dd) {
  if (stg == 0) return ((u >> 4) << 6) | (dd << 4) | ((u & 3) << 2) | ((u >> 2) & 3);
  if (stg == 1) return ((u >> 2) << 4) | (dd << 2) | (u & 3);
  return (u << 2) | dd;                       // stg 2
}
static __device__ __forceinline__ int shuf_out(int stg, int u, int dd) {
  if (stg == 0) return (dd << 6) | ((u & 15) << 2) | (u >> 4);
  if (stg == 1) return ((u >> 4) << 6) | (dd << 4) | ((u & 3) << 2) | ((u >> 2) & 3);
  if (stg == 2) return ((u >> 2) << 4) | (dd << 2) | (u & 3);
  return (u << 2) | dd;                       // stg 3
}

// full LDS state wipe: thread t zeroes its ENTIRE 144-B row t (9 x 16 B).
static __device__ __forceinline__ void zero_state(unsigned short* st, int t) {
  f32x4 z = {0.f, 0.f, 0.f, 0.f};
  char* p = (char*)st + t * 144;
  #pragma unroll
  for (int i = 0; i < 9; ++i) *(f32x4*)(p + i * 16) = z;
}

// one MFMA stage from LDS state: 8x ds_read_b128 (A), 6x b128 (B, L2-hot),
// 24 MFMA. Row stride 144 B: bank = 4*(c15+quad) mod 32, 8 lanes per
// 4-bank group -> conflict-free A reads.
static __device__ __forceinline__ void mfma_stage(
    const unsigned short* st, const unsigned short* __restrict__ Bf,
    int abase, int lane, f32x4 acc[4][3]) {
  short8 af[4][2];
  #pragma unroll
  for (int rt = 0; rt < 4; ++rt) {
    af[rt][0] = *(const short8*)((const char*)st + abase + rt * 2304);
    af[rt][1] = *(const short8*)((const char*)st + abase + rt * 2304 + 64);
  }
  short8 bfr[3][2];
  #pragma unroll
  for (int nt = 0; nt < 3; ++nt) {
    bfr[nt][0] = *(const short8*)&Bf[(nt * 2 + 0) * 512 + lane * 8];
    bfr[nt][1] = *(const short8*)&Bf[(nt * 2 + 1) * 512 + lane * 8];
  }
  #pragma unroll
  for (int rt = 0; rt < 4; ++rt)
    #pragma unroll
    for (int nt = 0; nt < 3; ++nt) {
      f32x4 a = {0.f, 0.f, 0.f, 0.f};
      a = __builtin_amdgcn_mfma_f32_16x16x32_bf16(af[rt][0], bfr[nt][0], a, 0, 0, 0);
      a = __builtin_amdgcn_mfma_f32_16x16x32_bf16(af[rt][1], bfr[nt][1], a, 0, 0, 0);
      acc[rt][nt] = a;
    }
}

// D -> LDS state write: per (rt,nt) one b64 (4 bf16, reg index i = new sub)
static __device__ __forceinline__ void write_stage_lds(
    unsigned short* st, const f32x4 acc[4][3], int w, int quad,
    const int* ddv, const int* sv, int stg, bool input_side) {
  #pragma unroll
  for (int rt = 0; rt < 4; ++rt) {
    const int u = w * 16 + rt * 4 + quad;
    #pragma unroll
    for (int nt = 0; nt < 3; ++nt) {
      if (sv[nt] < 10) {
        const int dd = ddv[nt];
        const int row = input_side ? shuf_in(stg, u, dd) : shuf_out(stg, u, dd);
        uint2 v;
        v.x = pack2(acc[rt][nt][0], acc[rt][nt][1]);
        v.y = pack2(acc[rt][nt][2], acc[rt][nt][3]);
        *(uint2*)((char*)st + row * 144 + sv[nt] * 8) = v;
      }
    }
  }
}

// ---------------- K0: prep --------------------------------------------------
// Bt[delta][c'']: delta = (d5..d10|d3d4|d1d2), c'' = (c1..c6|c9c10|c7c8)
// bf1/bf3: [stg][nt][kc][lane][8] bf16, n = nt*16+c15 -> (dd=n/12, s=n%12),
//          k = kc*32+quad*8+j -> (c=k>>2, pi=k&3); zero if k>=40 or s>=10.
__global__ __launch_bounds__(256) void k0_prep(
    const float* __restrict__ ic, const float* __restrict__ oc,
    const float* __restrict__ cc, unsigned short* __restrict__ Bt,
    float* __restrict__ c2x, unsigned short* __restrict__ bf1,
    unsigned short* __restrict__ bf3, unsigned short* __restrict__ bf3l) {
  const int t = threadIdx.x;
  const int bx = blockIdx.x;
  if (bx < 1024) {
    const int dly = bx;
    const int D = (dly & 3) * 256 + ((dly >> 2) & 3) * 64 + (dly >> 4);
    const int uC = (t >> 2) * 16 + (t & 3);   // C for c''=4t+j is uC + j*4
    ushort4 pk;
    pk.x = f2bf(cc[(size_t)(uC + 0) * 1024 + D]);
    pk.y = f2bf(cc[(size_t)(uC + 4) * 1024 + D]);
    pk.z = f2bf(cc[(size_t)(uC + 8) * 1024 + D]);
    pk.w = f2bf(cc[(size_t)(uC + 12) * 1024 + D]);
    *(ushort4*)&Bt[(size_t)dly * 1024 + 4 * t] = pk;
  } else if (bx == 1024) {
    // c2x[L][w=(c1c2)][pi=(p1p2)][s]  (f32, stage X)
    for (int idx = t; idx < 1600; idx += 256) {
      int L = idx / 160, rem = idx - L * 160;
      int w = rem / 40, r2 = rem - w * 40;
      int pi = r2 / 10, s = r2 - pi * 10;
      int p1 = pi >> 1, p2 = pi & 1, c1 = w >> 1, c2v = w & 1;
      float a = 0.f;
      for (int r1 = 0; r1 < 10; ++r1)
        a += ic[L * 40 + p1 * 20 + c1 * 10 + r1] *
             ic[400 + r1 * 40 + p2 * 20 + c2v * 10 + s];
      c2x[idx] = a;
    }
  } else if (bx == 1025) {
    // bf1: input stages, core pairs (2,3)..(8,9); pi = consumed x-bits,
    // dd = produced central bits; c = left-bond rank
    for (int idx = t; idx < 12288; idx += 256) {
      int j = idx & 7, lane = (idx >> 3) & 63, kc = (idx >> 9) & 1;
      int g2 = idx >> 10, stg = g2 / 3, nt = g2 - stg * 3;
      int c15 = lane & 15, quad = lane >> 4;
      int n = nt * 16 + c15, dd = n / 12, s = n - dd * 12;
      int k = kc * 32 + quad * 8 + j, c = k >> 2, pi = k & 3;
      float v = 0.f;
      if (k < 40 && s < 10) {
        int p1 = pi >> 1, p2 = pi & 1, d1 = dd >> 1, d2 = dd & 1;
        const float* A = ic + (2 * stg + 2) * 400;
        const float* B = ic + (2 * stg + 3) * 400;
        for (int tt = 0; tt < 10; ++tt)
          v += A[c * 40 + p1 * 20 + d1 * 10 + tt] *
               B[tt * 40 + p2 * 20 + d2 * 10 + s];
      }
      bf1[idx] = f2bf(v);
    }
  } else if (bx == 1026) {
    // bf3: output stages, core pairs (0,1)..(6,7); pi = consumed d-bits,
    // dd = produced output bits
    for (int idx = t; idx < 12288; idx += 256) {
      int j = idx & 7, lane = (idx >> 3) & 63, kc = (idx >> 9) & 1;
      int g2 = idx >> 10, stg = g2 / 3, nt = g2 - stg * 3;
      int c15 = lane & 15, quad = lane >> 4;
      int n = nt * 16 + c15, dd = n / 12, s = n - dd * 12;
      int k = kc * 32 + quad * 8 + j, c = k >> 2, pi = k & 3;
      float v = 0.f;
      if (k < 40 && s < 10) {
        int d1 = pi >> 1, d2 = pi & 1, p1 = dd >> 1, p2 = dd & 1;
        const float* A = oc + (2 * stg) * 400;
        const float* B = oc + (2 * stg + 1) * 400;
        for (int tt = 0; tt < 10; ++tt)
          v += A[c * 40 + p1 * 20 + d1 * 10 + tt] *
               B[tt * 40 + p2 * 20 + d2 * 10 + s];
      }
      bf3[idx] = f2bf(v);
    }
  } else {
    // bf3l[L][kc][lane][8]: cores (8,9), ring-trace (right bond = L) folded;
    // N = 4 (dd = p'9p'10 at n = c15 < 4), zero elsewhere
    for (int idx = t; idx < 10240; idx += 256) {
      int j = idx & 7, lane = (idx >> 3) & 63, kc = (idx >> 9) & 1, L = idx >> 10;
      int c15 = lane & 15, quad = lane >> 4;
      int k = kc * 32 + quad * 8 + j, c = k >> 2, pi = k & 3;
      float v = 0.f;
      if (k < 40 && c15 < 4) {
        int dd = c15, d1 = pi >> 1, d2 = pi & 1, p1 = dd >> 1, p2 = dd & 1;
        for (int tt = 0; tt < 10; ++tt)
          v += oc[8 * 400 + c * 40 + p1 * 20 + d1 * 10 + tt] *
               oc[9 * 400 + tt * 40 + p2 * 20 + d2 * 10 + L];
      }
      bf3l[idx] = f2bf(v);
    }
  }
}

// ---------------- K1: input sweep (stage X VALU + 4 MFMA stages) -----------
__global__ __launch_bounds__(256) void k1_insweep(
    const float* __restrict__ x, const float* __restrict__ c2x,
    const unsigned short* __restrict__ bf1, unsigned short* __restrict__ S) {
  __shared__ __align__(16) unsigned short st[256 * 72];
  const int t = threadIdx.x, bx = blockIdx.x;
  const int b = bx / 10, L = bx - b * 10;
  const int lane = t & 63, w = t >> 6;
  const int c15 = lane & 15, quad = lane >> 4;
  int ddv[3], sv[3];
  #pragma unroll
  for (int nt = 0; nt < 3; ++nt) {
    int n = nt * 16 + c15; ddv[nt] = n / 12; sv[nt] = n - ddv[nt] * 12;
  }
  const int abase = (w * 64 + c15) * 144 + quad * 16;
  zero_state(st, t);
  __syncthreads();
  // ---- stage X: absorb x top bit-pairs via fused cores (0,1), K=4 ----
  {
    const float* xb = x + (size_t)b * 1024;
    const float* C2 = c2x + L * 160 + w * 40;
    float accx[4][10];
    #pragma unroll
    for (int g = 0; g < 4; ++g)
      #pragma unroll
      for (int s = 0; s < 10; ++s) accx[g][s] = 0.f;
    #pragma unroll
    for (int pi = 0; pi < 4; ++pi) {
      float xv[4];
      #pragma unroll
      for (int g = 0; g < 4; ++g) xv[g] = xb[pi * 256 + g * 64 + lane];
      #pragma unroll
      for (int s = 0; s < 10; ++s) {
        const float bv = C2[pi * 10 + s];
        #pragma unroll
        for (int g = 0; g < 4; ++g) accx[g][s] = fmaf(xv[g], bv, accx[g][s]);
      }
    }
    const int row = w * 64 + c15 * 4 + quad;   // (c1c2 | p7..p10 | p5p6)
    #pragma unroll
    for (int s = 0; s < 10; ++s) {
      uint2 v;
      v.x = pack2(accx[0][s], accx[1][s]);
      v.y = pack2(accx[2][s], accx[3][s]);
      *(uint2*)((char*)st + row * 144 + s * 8) = v;
    }
  }
  __syncthreads();
  // ---- MFMA stages 0..3 (core pairs (2,3)..(8,9)) ----
  f32x4 acc[4][3];
  #pragma unroll
  for (int stg = 0; stg < 4; ++stg) {
    mfma_stage(st, bf1 + stg * 3072, abase, lane, acc);
    if (stg < 3) {
      __syncthreads();
      write_stage_lds(st, acc, w, quad, ddv, sv, stg, true);
      __syncthreads();
    } else {
      // final: S col c'' = u*16 + dd*4 + i  (i = c7c8)
      #pragma unroll
      for (int rt = 0; rt < 4; ++rt) {
        const int u = w * 16 + rt * 4 + quad;
        #pragma unroll
        for (int nt = 0; nt < 3; ++nt) {
          if (sv[nt] < 10) {
            uint2 v;
            v.x = pack2(acc[rt][nt][0], acc[rt][nt][1]);
            v.y = pack2(acc[rt][nt][2], acc[rt][nt][3]);
            *(uint2*)&S[((size_t)(bx * 10 + sv[nt])) * 1024 + u * 16 + ddv[nt] * 4] = v;
          }
        }
      }
    }
  }
}

// ---------------- K2: MFMA GEMM, M=1024 (delta) x N=51200 x K=1024 ---------
__global__ __launch_bounds__(256) void k2_gemm(
    const unsigned short* __restrict__ A,   // Bt [1024][1024]  (af side)
    const unsigned short* __restrict__ B,   // S  [51200][1024] (bf side)
    unsigned short* __restrict__ U2a,       // [5120][256][32] bf16
    unsigned short* __restrict__ U2b) {     // [5120][256][8]  bf16
  __shared__ __align__(16) unsigned short Atile[128 * 32];
  __shared__ __align__(16) unsigned short Btile[128 * 32];
  const int t = threadIdx.x, bx = blockIdx.x;
  const int bm = bx & 7, bn = bx >> 3;
  const int wave = t >> 6, lane = t & 63;
  const int wm = wave & 1, wn = wave >> 1;

  f32x4 acc[4][4];
  #pragma unroll
  for (int i = 0; i < 4; ++i)
    #pragma unroll
    for (int j = 0; j < 4; ++j) acc[i][j] = (f32x4){0.f, 0.f, 0.f, 0.f};

  const int arow = t >> 2, achk = t & 3;
  const unsigned short* Ag = A + (size_t)(bm * 128 + arow) * 1024 + achk * 8;
  const unsigned short* Bg = B + (size_t)(bn * 128 + arow) * 1024 + achk * 8;
  char* ldsA = (char*)Atile + wave * 1024;
  char* ldsB = (char*)Btile + wave * 1024;

  for (int k0 = 0; k0 < 1024; k0 += 32) {
    __builtin_amdgcn_global_load_lds(
        (const __attribute__((address_space(1))) void*)(Ag + k0),
        (__attribute__((address_space(3))) void*)ldsA, 16, 0, 0);
    __builtin_amdgcn_global_load_lds(
        (const __attribute__((address_space(1))) void*)(Ag + 64 * 1024 + k0),
        (__attribute__((address_space(3))) void*)(ldsA + 4096), 16, 0, 0);
    __builtin_amdgcn_global_load_lds(
        (const __attribute__((address_space(1))) void*)(Bg + k0),
        (__attribute__((address_space(3))) void*)ldsB, 16, 0, 0);
    __builtin_amdgcn_global_load_lds(
        (const __attribute__((address_space(1))) void*)(Bg + 64 * 1024 + k0),
        (__attribute__((address_space(3))) void*)(ldsB + 4096), 16, 0, 0);
    __syncthreads();
    short8 af[4], bf[4];
    const int kq = (lane >> 4) * 8;
    #pragma unroll
    for (int mt = 0; mt < 4; ++mt)
      af[mt] = *(const short8*)&Atile[(wm * 64 + mt * 16 + (lane & 15)) * 32 + kq];
    #pragma unroll
    for (int nt = 0; nt < 4; ++nt)
      bf[nt] = *(const short8*)&Btile[(wn * 64 + nt * 16 + (lane & 15)) * 32 + kq];
    #pragma unroll
    for (int mt = 0; mt < 4; ++mt)
      #pragma unroll
      for (int nt = 0; nt < 4; ++nt)
        acc[mt][nt] = __builtin_amdgcn_mfma_f32_16x16x32_bf16(
            af[mt], bf[nt], acc[mt][nt], 0, 0, 0);
    __syncthreads();
  }
  // epilogue: D rows = delta (i = d1d2), cols = S rows (bl, r)
  const int quad = lane >> 4;
  const int col0 = bn * 128 + wn * 64 + (lane & 15);
  const int row0 = bm * 128 + wm * 64;
  #pragma unroll
  for (int nt = 0; nt < 4; ++nt) {
    const int n = col0 + nt * 16;
    const int bl = n / 10;
    const int r = n - bl * 10;
    char* dst = (r < 8)
        ? (char*)U2a + (size_t)bl * 16384 + (size_t)r * 8
        : (char*)U2b + (size_t)bl * 4096 + (size_t)(r - 8) * 8;
    const int rb = (r < 8) ? 64 : 16;
    #pragma unroll
    for (int mt = 0; mt < 4; ++mt) {
      const int mp = (row0 + mt * 16 + quad * 4) >> 2;   // delta>>2
      uint2 v;
      v.x = pack2(acc[mt][nt][0], acc[mt][nt][1]);
      v.y = pack2(acc[mt][nt][2], acc[mt][nt][3]);
      *(uint2*)(dst + (size_t)mp * rb) = v;
    }
  }
}

// ---------------- K3: output sweep (5 MFMA stages + trace + bias) ----------
__global__ __launch_bounds__(256) void k3_outsweep(
    const unsigned short* __restrict__ U2a, const unsigned short* __restrict__ U2b,
    const unsigned short* __restrict__ bf3, const unsigned short* __restrict__ bf3l,
    const float* __restrict__ bias, float* __restrict__ out) {
  __shared__ __align__(16) unsigned short st[256 * 72];
  const int t = threadIdx.x, bx = blockIdx.x;
  const int b = bx / 10, L = bx - b * 10;
  const int lane = t & 63, w = t >> 6;
  const int c15 = lane & 15, quad = lane >> 4;
  int ddv[3], sv[3];
  #pragma unroll
  for (int nt = 0; nt < 3; ++nt) {
    int n = nt * 16 + c15; ddv[nt] = n / 12; sv[nt] = n - ddv[nt] * 12;
  }
  const int abase = (w * 64 + c15) * 144 + quad * 16;
  zero_state(st, t);
  __syncthreads();
  f32x4 acc[4][3];
  // ---- stage 0: A-frags from global U2 (coalesced), cores (0,1) ----
  {
    short8 af[4][2], bfr[3][2];
    const char* Ua = (const char*)U2a + (size_t)bx * 16384;
    const char* Ub = (const char*)U2b + (size_t)bx * 4096;
    #pragma unroll
    for (int rt = 0; rt < 4; ++rt) {
      const int m = w * 64 + rt * 16 + c15;
      af[rt][0] = *(const short8*)(Ua + m * 64 + quad * 16);
      af[rt][1] = *(const short8*)(Ub + m * 16);   // quads 1-3: k>=40, B=0
    }
    #pragma unroll
    for (int nt = 0; nt < 3; ++nt) {
      bfr[nt][0] = *(const short8*)&bf3[(nt * 2 + 0) * 512 + lane * 8];
      bfr[nt][1] = *(const short8*)&bf3[(nt * 2 + 1) * 512 + lane * 8];
    }
    #pragma unroll
    for (int rt = 0; rt < 4; ++rt)
      #pragma unroll
      for (int nt = 0; nt < 3; ++nt) {
        f32x4 a = {0.f, 0.f, 0.f, 0.f};
        a = __builtin_amdgcn_mfma_f32_16x16x32_bf16(af[rt][0], bfr[nt][0], a, 0, 0, 0);
        a = __builtin_amdgcn_mfma_f32_16x16x32_bf16(af[rt][1], bfr[nt][1], a, 0, 0, 0);
        acc[rt][nt] = a;
      }
    write_stage_lds(st, acc, w, quad, ddv, sv, 0, false);
    __syncthreads();
  }
  // ---- stages 1..3 (cores (2,3),(4,5),(6,7)) ----
  #pragma unroll
  for (int stg = 1; stg < 4; ++stg) {
    mfma_stage(st, bf3 + stg * 3072, abase, lane, acc);
    __syncthreads();
    write_stage_lds(st, acc, w, quad, ddv, sv, stg, false);
    __syncthreads();
  }
  // ---- stage 4: cores (8,9) + ring trace, N=4; bias + atomicAdd ----
  {
    const unsigned short* Bf = bf3l + L * 1024;
    const short8 b0 = *(const short8*)&Bf[lane * 8];
    const short8 b1 = *(const short8*)&Bf[512 + lane * 8];
    #pragma unroll
    for (int rt = 0; rt < 4; ++rt) {
      const short8 a0 = *(const short8*)((const char*)st + abase + rt * 2304);
      const short8 a1 = *(const short8*)((const char*)st + abase + rt * 2304 + 64);
      f32x4 a = {0.f, 0.f, 0.f, 0.f};
      a = __builtin_amdgcn_mfma_f32_16x16x32_bf16(a0, b0, a, 0, 0, 0);
      a = __builtin_amdgcn_mfma_f32_16x16x32_bf16(a1, b1, a, 0, 0, 0);
      if (c15 < 4) {
        const int u = w * 16 + rt * 4 + quad;
        #pragma unroll
        for (int i = 0; i < 4; ++i) {
          const int idx = u * 16 + i * 4 + c15;   // p'1..p'10
          float v = a[i];
          if (L == 0) v += bias[idx];
          atomicAdd(&out[(size_t)b * 1024 + idx], v);
        }
      }
    }
  }
}

// ---------------- launch ----------------------------------------------------
extern "C" void kernel_launch(void* const* d_in, const int* in_sizes, int n_in,
                              void* d_out, int out_size, void* d_ws, size_t ws_size,
                              hipStream_t stream) {
  (void)in_sizes; (void)n_in; (void)ws_size;
  const float* x    = (const float*)d_in[0];
  const float* ic   = (const float*)d_in[1];
  const float* oc   = (const float*)d_in[2];
  const float* cc   = (const float*)d_in[3];
  const float* bias = (const float*)d_in[4];
  float* out = (float*)d_out;

  char* ws = (char*)d_ws;
  unsigned short* S    = (unsigned short*)(ws);              // 104857600 B
  unsigned short* U2a  = (unsigned short*)(ws + 104857600);  //  83886080 B
  unsigned short* U2b  = (unsigned short*)(ws + 188743680);  //  20971520 B
  unsigned short* Bt   = (unsigned short*)(ws + 209715200);  //   2097152 B
  float*          c2x  = (float*)(ws + 211812352);           //      6400 B
  unsigned short* bf1  = (unsigned short*)(ws + 211818752);  //     24576 B
  unsigned short* bf3  = (unsigned short*)(ws + 211843328);  //     24576 B
  unsigned short* bf3l = (unsigned short*)(ws + 211867904);  //     20480 B

  hipMemsetAsync(d_out, 0, (size_t)out_size * sizeof(float), stream);
  k0_prep<<<1028, 256, 0, stream>>>(ic, oc, cc, Bt, c2x, bf1, bf3, bf3l);
  k1_insweep<<<5120, 256, 0, stream>>>(x, c2x, bf1, S);
  k2_gemm<<<3200, 256, 0, stream>>>(Bt, S, U2a, U2b);
  k3_outsweep<<<5120, 256, 0, stream>>>(U2a, U2b, bf3, bf3l, bias, out);
}

// Round 6
// 359.360 us; speedup vs baseline: 3.3956x; 1.1156x over previous
//
#include <hip/hip_runtime.h>
#include <cstdint>
#include <cstddef>

// ---------------------------------------------------------------------------
// TWLayer — all-MFMA pipeline (R6 = R4/R5-correct + K2 XCD swizzle).
//   K0: Bt[delta][c''] (central, both sides permuted), c2x (stage-X f32),
//       per-stage MFMA B-fragment tables bf1/bf3/bf3l zero-padded to
//       K=64 / N=48 so A-side pad reads are annihilated (B=0).
//   K1: per (b,L): stage X on VALU (K=4), then 4 MFMA stages with LDS-resident
//       bf16 state; inter-stage bit permutation folded into D->LDS addressing.
//   K2: MFMA GEMM, M=1024 (central delta side) x N=51200 (S rows) x K=1024.
//       R6: XCD-aware swizzle — the 8 bm-blocks sharing one S tile (same bn)
//       are placed on the SAME XCD (bx%8 round-robin assumption) so the tile
//       is fetched from HBM once, not 8x. R5 counters: FETCH 414 MB vs 102
//       ideal, HBM-bound at 3.3 TB/s.
//   K3: mirror of K1 on the output chain; trace + bias + atomicAdd.
// ---------------------------------------------------------------------------

typedef __attribute__((ext_vector_type(8))) short short8;   // 8 x bf16
typedef __attribute__((ext_vector_type(4))) float f32x4;

static __device__ __forceinline__ unsigned short f2bf(float f) {
  union { float f; unsigned int u; } v; v.f = f;
  unsigned int r = v.u + 0x7FFFu + ((v.u >> 16) & 1u);   // RNE
  return (unsigned short)(r >> 16);
}
static __device__ __forceinline__ unsigned int pack2(float a, float b) {
  return (unsigned int)f2bf(a) | ((unsigned int)f2bf(b) << 16);
}

// ---- stage-permutation row maps (element-verified; g always = m&3) --------
static __device__ __forceinline__ int shuf_in(int stg, int u, int dd) {
  if (stg == 0) return ((u >> 4) << 6) | (dd << 4) | ((u & 3) << 2) | ((u >> 2) & 3);
  if (stg == 1) return ((u >> 2) << 4) | (dd << 2) | (u & 3);
  return (u << 2) | dd;                       // stg 2
}
static __device__ __forceinline__ int shuf_out(int stg, int u, int dd) {
  if (stg == 0) return (dd << 6) | ((u & 15) << 2) | (u >> 4);
  if (stg == 1) return ((u >> 4) << 6) | (dd << 4) | ((u & 3) << 2) | ((u >> 2) & 3);
  if (stg == 2) return ((u >> 2) << 4) | (dd << 2) | (u & 3);
  return (u << 2) | dd;                       // stg 3
}

// full LDS row wipe: zero the ENTIRE 144-B row `row` (9 x 16 B).
static __device__ __forceinline__ void zero_row(unsigned short* st, int row) {
  f32x4 z = {0.f, 0.f, 0.f, 0.f};
  char* p = (char*)st + row * 144;
  #pragma unroll
  for (int i = 0; i < 9; ++i) *(f32x4*)(p + i * 16) = z;
}

// one MFMA stage from LDS state: 8x ds_read_b128 (A), 6x b128 (B, L2-hot),
// 24 MFMA. Row stride 144 B: bank = 4*(c15+quad) mod 32, 8 lanes per
// 4-bank group -> conflict-free A reads.
static __device__ __forceinline__ void mfma_stage(
    const unsigned short* st, const unsigned short* __restrict__ Bf,
    int abase, int lane, f32x4 acc[4][3]) {
  short8 af[4][2];
  #pragma unroll
  for (int rt = 0; rt < 4; ++rt) {
    af[rt][0] = *(const short8*)((const char*)st + abase + rt * 2304);
    af[rt][1] = *(const short8*)((const char*)st + abase + rt * 2304 + 64);
  }
  short8 bfr[3][2];
  #pragma unroll
  for (int nt = 0; nt < 3; ++nt) {
    bfr[nt][0] = *(const short8*)&Bf[(nt * 2 + 0) * 512 + lane * 8];
    bfr[nt][1] = *(const short8*)&Bf[(nt * 2 + 1) * 512 + lane * 8];
  }
  #pragma unroll
  for (int rt = 0; rt < 4; ++rt)
    #pragma unroll
    for (int nt = 0; nt < 3; ++nt) {
      f32x4 a = {0.f, 0.f, 0.f, 0.f};
      a = __builtin_amdgcn_mfma_f32_16x16x32_bf16(af[rt][0], bfr[nt][0], a, 0, 0, 0);
      a = __builtin_amdgcn_mfma_f32_16x16x32_bf16(af[rt][1], bfr[nt][1], a, 0, 0, 0);
      acc[rt][nt] = a;
    }
}

// D -> LDS state write: per (rt,nt) one b64 (4 bf16, reg index i = new sub)
static __device__ __forceinline__ void write_stage_lds(
    unsigned short* st, const f32x4 acc[4][3], int w, int quad,
    const int* ddv, const int* sv, int stg, bool input_side) {
  #pragma unroll
  for (int rt = 0; rt < 4; ++rt) {
    const int u = w * 16 + rt * 4 + quad;
    #pragma unroll
    for (int nt = 0; nt < 3; ++nt) {
      if (sv[nt] < 10) {
        const int dd = ddv[nt];
        const int row = input_side ? shuf_in(stg, u, dd) : shuf_out(stg, u, dd);
        uint2 v;
        v.x = pack2(acc[rt][nt][0], acc[rt][nt][1]);
        v.y = pack2(acc[rt][nt][2], acc[rt][nt][3]);
        *(uint2*)((char*)st + row * 144 + sv[nt] * 8) = v;
      }
    }
  }
}

// ---------------- K0: prep --------------------------------------------------
// Bt[delta][c'']: delta = (d5..d10|d3d4|d1d2), c'' = (c1..c6|c9c10|c7c8)
// bf1/bf3: [stg][nt][kc][lane][8] bf16, n = nt*16+c15 -> (dd=n/12, s=n%12),
//          k = kc*32+quad*8+j -> (c=k>>2, pi=k&3); zero if k>=40 or s>=10.
__global__ __launch_bounds__(256) void k0_prep(
    const float* __restrict__ ic, const float* __restrict__ oc,
    const float* __restrict__ cc, unsigned short* __restrict__ Bt,
    float* __restrict__ c2x, unsigned short* __restrict__ bf1,
    unsigned short* __restrict__ bf3, unsigned short* __restrict__ bf3l) {
  const int t = threadIdx.x;
  const int bx = blockIdx.x;
  if (bx < 1024) {
    const int dly = bx;
    const int D = (dly & 3) * 256 + ((dly >> 2) & 3) * 64 + (dly >> 4);
    const int uC = (t >> 2) * 16 + (t & 3);   // C for c''=4t+j is uC + j*4
    ushort4 pk;
    pk.x = f2bf(cc[(size_t)(uC + 0) * 1024 + D]);
    pk.y = f2bf(cc[(size_t)(uC + 4) * 1024 + D]);
    pk.z = f2bf(cc[(size_t)(uC + 8) * 1024 + D]);
    pk.w = f2bf(cc[(size_t)(uC + 12) * 1024 + D]);
    *(ushort4*)&Bt[(size_t)dly * 1024 + 4 * t] = pk;
  } else if (bx == 1024) {
    // c2x[L][w=(c1c2)][pi=(p1p2)][s]  (f32, stage X)
    for (int idx = t; idx < 1600; idx += 256) {
      int L = idx / 160, rem = idx - L * 160;
      int w = rem / 40, r2 = rem - w * 40;
      int pi = r2 / 10, s = r2 - pi * 10;
      int p1 = pi >> 1, p2 = pi & 1, c1 = w >> 1, c2v = w & 1;
      float a = 0.f;
      for (int r1 = 0; r1 < 10; ++r1)
        a += ic[L * 40 + p1 * 20 + c1 * 10 + r1] *
             ic[400 + r1 * 40 + p2 * 20 + c2v * 10 + s];
      c2x[idx] = a;
    }
  } else if (bx == 1025) {
    // bf1: input stages, core pairs (2,3)..(8,9); pi = consumed x-bits,
    // dd = produced central bits; c = left-bond rank
    for (int idx = t; idx < 12288; idx += 256) {
      int j = idx & 7, lane = (idx >> 3) & 63, kc = (idx >> 9) & 1;
      int g2 = idx >> 10, stg = g2 / 3, nt = g2 - stg * 3;
      int c15 = lane & 15, quad = lane >> 4;
      int n = nt * 16 + c15, dd = n / 12, s = n - dd * 12;
      int k = kc * 32 + quad * 8 + j, c = k >> 2, pi = k & 3;
      float v = 0.f;
      if (k < 40 && s < 10) {
        int p1 = pi >> 1, p2 = pi & 1, d1 = dd >> 1, d2 = dd & 1;
        const float* A = ic + (2 * stg + 2) * 400;
        const float* B = ic + (2 * stg + 3) * 400;
        for (int tt = 0; tt < 10; ++tt)
          v += A[c * 40 + p1 * 20 + d1 * 10 + tt] *
               B[tt * 40 + p2 * 20 + d2 * 10 + s];
      }
      bf1[idx] = f2bf(v);
    }
  } else if (bx == 1026) {
    // bf3: output stages, core pairs (0,1)..(6,7); pi = consumed d-bits,
    // dd = produced output bits
    for (int idx = t; idx < 12288; idx += 256) {
      int j = idx & 7, lane = (idx >> 3) & 63, kc = (idx >> 9) & 1;
      int g2 = idx >> 10, stg = g2 / 3, nt = g2 - stg * 3;
      int c15 = lane & 15, quad = lane >> 4;
      int n = nt * 16 + c15, dd = n / 12, s = n - dd * 12;
      int k = kc * 32 + quad * 8 + j, c = k >> 2, pi = k & 3;
      float v = 0.f;
      if (k < 40 && s < 10) {
        int d1 = pi >> 1, d2 = pi & 1, p1 = dd >> 1, p2 = dd & 1;
        const float* A = oc + (2 * stg) * 400;
        const float* B = oc + (2 * stg + 1) * 400;
        for (int tt = 0; tt < 10; ++tt)
          v += A[c * 40 + p1 * 20 + d1 * 10 + tt] *
               B[tt * 40 + p2 * 20 + d2 * 10 + s];
      }
      bf3[idx] = f2bf(v);
    }
  } else {
    // bf3l[L][kc][lane][8]: cores (8,9), ring-trace (right bond = L) folded;
    // N = 4 (dd = p'9p'10 at n = c15 < 4), zero elsewhere
    for (int idx = t; idx < 10240; idx += 256) {
      int j = idx & 7, lane = (idx >> 3) & 63, kc = (idx >> 9) & 1, L = idx >> 10;
      int c15 = lane & 15, quad = lane >> 4;
      int k = kc * 32 + quad * 8 + j, c = k >> 2, pi = k & 3;
      float v = 0.f;
      if (k < 40 && c15 < 4) {
        int dd = c15, d1 = pi >> 1, d2 = pi & 1, p1 = dd >> 1, p2 = dd & 1;
        for (int tt = 0; tt < 10; ++tt)
          v += oc[8 * 400 + c * 40 + p1 * 20 + d1 * 10 + tt] *
               oc[9 * 400 + tt * 40 + p2 * 20 + d2 * 10 + L];
      }
      bf3l[idx] = f2bf(v);
    }
  }
}

// ---------------- K1: input sweep (stage X VALU + 4 MFMA stages) -----------
__global__ __launch_bounds__(256, 4) void k1_insweep(
    const float* __restrict__ x, const float* __restrict__ c2x,
    const unsigned short* __restrict__ bf1, unsigned short* __restrict__ S) {
  __shared__ __align__(16) unsigned short st[256 * 72];
  const int t = threadIdx.x, bx = blockIdx.x;
  const int b = bx / 10, L = bx - b * 10;
  const int lane = t & 63, w = t >> 6;
  const int c15 = lane & 15, quad = lane >> 4;
  int ddv[3], sv[3];
  #pragma unroll
  for (int nt = 0; nt < 3; ++nt) {
    int n = nt * 16 + c15; ddv[nt] = n / 12; sv[nt] = n - ddv[nt] * 12;
  }
  const int abase = (w * 64 + c15) * 144 + quad * 16;
  // ---- stage X: absorb x top bit-pairs via fused cores (0,1), K=4 ----
  // Each thread zeroes exactly the row it then writes (bijection of t), so
  // no barrier is needed between wipe and write (per-thread program order).
  {
    const int row = w * 64 + c15 * 4 + quad;   // (c1c2 | p7..p10 | p5p6)
    zero_row(st, row);
    const float* xb = x + (size_t)b * 1024;
    const float* C2 = c2x + L * 160 + w * 40;
    float accx[4][10];
    #pragma unroll
    for (int g = 0; g < 4; ++g)
      #pragma unroll
      for (int s = 0; s < 10; ++s) accx[g][s] = 0.f;
    #pragma unroll
    for (int pi = 0; pi < 4; ++pi) {
      float xv[4];
      #pragma unroll
      for (int g = 0; g < 4; ++g) xv[g] = xb[pi * 256 + g * 64 + lane];
      #pragma unroll
      for (int s = 0; s < 10; ++s) {
        const float bv = C2[pi * 10 + s];
        #pragma unroll
        for (int g = 0; g < 4; ++g) accx[g][s] = fmaf(xv[g], bv, accx[g][s]);
      }
    }
    #pragma unroll
    for (int s = 0; s < 10; ++s) {
      uint2 v;
      v.x = pack2(accx[0][s], accx[1][s]);
      v.y = pack2(accx[2][s], accx[3][s]);
      *(uint2*)((char*)st + row * 144 + s * 8) = v;
    }
  }
  __syncthreads();
  // ---- MFMA stages 0..3 (core pairs (2,3)..(8,9)) ----
  f32x4 acc[4][3];
  #pragma unroll
  for (int stg = 0; stg < 4; ++stg) {
    mfma_stage(st, bf1 + stg * 3072, abase, lane, acc);
    if (stg < 3) {
      __syncthreads();
      write_stage_lds(st, acc, w, quad, ddv, sv, stg, true);
      __syncthreads();
    } else {
      // final: S col c'' = u*16 + dd*4 + i  (i = c7c8)
      #pragma unroll
      for (int rt = 0; rt < 4; ++rt) {
        const int u = w * 16 + rt * 4 + quad;
        #pragma unroll
        for (int nt = 0; nt < 3; ++nt) {
          if (sv[nt] < 10) {
            uint2 v;
            v.x = pack2(acc[rt][nt][0], acc[rt][nt][1]);
            v.y = pack2(acc[rt][nt][2], acc[rt][nt][3]);
            *(uint2*)&S[((size_t)(bx * 10 + sv[nt])) * 1024 + u * 16 + ddv[nt] * 4] = v;
          }
        }
      }
    }
  }
}

// ---------------- K2: MFMA GEMM, M=1024 (delta) x N=51200 x K=1024 ---------
__global__ __launch_bounds__(256) void k2_gemm(
    const unsigned short* __restrict__ A,   // Bt [1024][1024]  (af side)
    const unsigned short* __restrict__ B,   // S  [51200][1024] (bf side)
    unsigned short* __restrict__ U2a,       // [5120][256][32] bf16
    unsigned short* __restrict__ U2b) {     // [5120][256][8]  bf16
  __shared__ __align__(16) unsigned short Atile[128 * 32];
  __shared__ __align__(16) unsigned short Btile[128 * 32];
  const int t = threadIdx.x, bx = blockIdx.x;
  // XCD-aware swizzle: blocks round-robin to XCDs by bx%8. Give each XCD a
  // disjoint set of bn (S tiles) and run all 8 bm for that bn on the SAME
  // XCD so the S tile is fetched into that XCD's L2 exactly once.
  const int xcd = bx & 7;
  const int i8 = bx >> 3;                  // 0..399
  const int bm = i8 & 7;                   // 8 M-tiles
  const int bn = (i8 >> 3) * 8 + xcd;      // 400 N-tiles, partitioned by XCD
  const int wave = t >> 6, lane = t & 63;
  const int wm = wave & 1, wn = wave >> 1;

  f32x4 acc[4][4];
  #pragma unroll
  for (int i = 0; i < 4; ++i)
    #pragma unroll
    for (int j = 0; j < 4; ++j) acc[i][j] = (f32x4){0.f, 0.f, 0.f, 0.f};

  const int arow = t >> 2, achk = t & 3;
  const unsigned short* Ag = A + (size_t)(bm * 128 + arow) * 1024 + achk * 8;
  const unsigned short* Bg = B + (size_t)(bn * 128 + arow) * 1024 + achk * 8;
  char* ldsA = (char*)Atile + wave * 1024;
  char* ldsB = (char*)Btile + wave * 1024;

  for (int k0 = 0; k0 < 1024; k0 += 32) {
    __builtin_amdgcn_global_load_lds(
        (const __attribute__((address_space(1))) void*)(Ag + k0),
        (__attribute__((address_space(3))) void*)ldsA, 16, 0, 0);
    __builtin_amdgcn_global_load_lds(
        (const __attribute__((address_space(1))) void*)(Ag + 64 * 1024 + k0),
        (__attribute__((address_space(3))) void*)(ldsA + 4096), 16, 0, 0);
    __builtin_amdgcn_global_load_lds(
        (const __attribute__((address_space(1))) void*)(Bg + k0),
        (__attribute__((address_space(3))) void*)ldsB, 16, 0, 0);
    __builtin_amdgcn_global_load_lds(
        (const __attribute__((address_space(1))) void*)(Bg + 64 * 1024 + k0),
        (__attribute__((address_space(3))) void*)(ldsB + 4096), 16, 0, 0);
    __syncthreads();
    short8 af[4], bf[4];
    const int kq = (lane >> 4) * 8;
    #pragma unroll
    for (int mt = 0; mt < 4; ++mt)
      af[mt] = *(const short8*)&Atile[(wm * 64 + mt * 16 + (lane & 15)) * 32 + kq];
    #pragma unroll
    for (int nt = 0; nt < 4; ++nt)
      bf[nt] = *(const short8*)&Btile[(wn * 64 + nt * 16 + (lane & 15)) * 32 + kq];
    #pragma unroll
    for (int mt = 0; mt < 4; ++mt)
      #pragma unroll
      for (int nt = 0; nt < 4; ++nt)
        acc[mt][nt] = __builtin_amdgcn_mfma_f32_16x16x32_bf16(
            af[mt], bf[nt], acc[mt][nt], 0, 0, 0);
    __syncthreads();
  }
  // epilogue: D rows = delta (i = d1d2), cols = S rows (bl, r)
  const int quad = lane >> 4;
  const int col0 = bn * 128 + wn * 64 + (lane & 15);
  const int row0 = bm * 128 + wm * 64;
  #pragma unroll
  for (int nt = 0; nt < 4; ++nt) {
    const int n = col0 + nt * 16;
    const int bl = n / 10;
    const int r = n - bl * 10;
    char* dst = (r < 8)
        ? (char*)U2a + (size_t)bl * 16384 + (size_t)r * 8
        : (char*)U2b + (size_t)bl * 4096 + (size_t)(r - 8) * 8;
    const int rb = (r < 8) ? 64 : 16;
    #pragma unroll
    for (int mt = 0; mt < 4; ++mt) {
      const int mp = (row0 + mt * 16 + quad * 4) >> 2;   // delta>>2
      uint2 v;
      v.x = pack2(acc[mt][nt][0], acc[mt][nt][1]);
      v.y = pack2(acc[mt][nt][2], acc[mt][nt][3]);
      *(uint2*)(dst + (size_t)mp * rb) = v;
    }
  }
}

// ---------------- K3: output sweep (5 MFMA stages + trace + bias) ----------
__global__ __launch_bounds__(256, 4) void k3_outsweep(
    const unsigned short* __restrict__ U2a, const unsigned short* __restrict__ U2b,
    const unsigned short* __restrict__ bf3, const unsigned short* __restrict__ bf3l,
    const float* __restrict__ bias, float* __restrict__ out) {
  __shared__ __align__(16) unsigned short st[256 * 72];
  const int t = threadIdx.x, bx = blockIdx.x;
  const int b = bx / 10, L = bx - b * 10;
  const int lane = t & 63, w = t >> 6;
  const int c15 = lane & 15, quad = lane >> 4;
  int ddv[3], sv[3];
  #pragma unroll
  for (int nt = 0; nt < 3; ++nt) {
    int n = nt * 16 + c15; ddv[nt] = n / 12; sv[nt] = n - ddv[nt] * 12;
  }
  const int abase = (w * 64 + c15) * 144 + quad * 16;
  zero_row(st, t);
  __syncthreads();
  f32x4 acc[4][3];
  // ---- stage 0: A-frags from global U2 (coalesced), cores (0,1) ----
  {
    short8 af[4][2], bfr[3][2];
    const char* Ua = (const char*)U2a + (size_t)bx * 16384;
    const char* Ub = (const char*)U2b + (size_t)bx * 4096;
    #pragma unroll
    for (int rt = 0; rt < 4; ++rt) {
      const int m = w * 64 + rt * 16 + c15;
      af[rt][0] = *(const short8*)(Ua + m * 64 + quad * 16);
      af[rt][1] = *(const short8*)(Ub + m * 16);   // quads 1-3: k>=40, B=0
    }
    #pragma unroll
    for (int nt = 0; nt < 3; ++nt) {
      bfr[nt][0] = *(const short8*)&bf3[(nt * 2 + 0) * 512 + lane * 8];
      bfr[nt][1] = *(const short8*)&bf3[(nt * 2 + 1) * 512 + lane * 8];
    }
    #pragma unroll
    for (int rt = 0; rt < 4; ++rt)
      #pragma unroll
      for (int nt = 0; nt < 3; ++nt) {
        f32x4 a = {0.f, 0.f, 0.f, 0.f};
        a = __builtin_amdgcn_mfma_f32_16x16x32_bf16(af[rt][0], bfr[nt][0], a, 0, 0, 0);
        a = __builtin_amdgcn_mfma_f32_16x16x32_bf16(af[rt][1], bfr[nt][1], a, 0, 0, 0);
        acc[rt][nt] = a;
      }
    write_stage_lds(st, acc, w, quad, ddv, sv, 0, false);
    __syncthreads();
  }
  // ---- stages 1..3 (cores (2,3),(4,5),(6,7)) ----
  #pragma unroll
  for (int stg = 1; stg < 4; ++stg) {
    mfma_stage(st, bf3 + stg * 3072, abase, lane, acc);
    __syncthreads();
    write_stage_lds(st, acc, w, quad, ddv, sv, stg, false);
    __syncthreads();
  }
  // ---- stage 4: cores (8,9) + ring trace, N=4; bias + atomicAdd ----
  {
    const unsigned short* Bf = bf3l + L * 1024;
    const short8 b0 = *(const short8*)&Bf[lane * 8];
    const short8 b1 = *(const short8*)&Bf[512 + lane * 8];
    #pragma unroll
    for (int rt = 0; rt < 4; ++rt) {
      const short8 a0 = *(const short8*)((const char*)st + abase + rt * 2304);
      const short8 a1 = *(const short8*)((const char*)st + abase + rt * 2304 + 64);
      f32x4 a = {0.f, 0.f, 0.f, 0.f};
      a = __builtin_amdgcn_mfma_f32_16x16x32_bf16(a0, b0, a, 0, 0, 0);
      a = __builtin_amdgcn_mfma_f32_16x16x32_bf16(a1, b1, a, 0, 0, 0);
      if (c15 < 4) {
        const int u = w * 16 + rt * 4 + quad;
        #pragma unroll
        for (int i = 0; i < 4; ++i) {
          const int idx = u * 16 + i * 4 + c15;   // p'1..p'10
          float v = a[i];
          if (L == 0) v += bias[idx];
          atomicAdd(&out[(size_t)b * 1024 + idx], v);
        }
      }
    }
  }
}

// ---------------- launch ----------------------------------------------------
extern "C" void kernel_launch(void* const* d_in, const int* in_sizes, int n_in,
                              void* d_out, int out_size, void* d_ws, size_t ws_size,
                              hipStream_t stream) {
  (void)in_sizes; (void)n_in; (void)ws_size;
  const float* x    = (const float*)d_in[0];
  const float* ic   = (const float*)d_in[1];
  const float* oc   = (const float*)d_in[2];
  const float* cc   = (const float*)d_in[3];
  const float* bias = (const float*)d_in[4];
  float* out = (float*)d_out;

  char* ws = (char*)d_ws;
  unsigned short* S    = (unsigned short*)(ws);              // 104857600 B
  unsigned short* U2a  = (unsigned short*)(ws + 104857600);  //  83886080 B
  unsigned short* U2b  = (unsigned short*)(ws + 188743680);  //  20971520 B
  unsigned short* Bt   = (unsigned short*)(ws + 209715200);  //   2097152 B
  float*          c2x  = (float*)(ws + 211812352);           //      6400 B
  unsigned short* bf1  = (unsigned short*)(ws + 211818752);  //     24576 B
  unsigned short* bf3  = (unsigned short*)(ws + 211843328);  //     24576 B
  unsigned short* bf3l = (unsigned short*)(ws + 211867904);  //     20480 B

  hipMemsetAsync(d_out, 0, (size_t)out_size * sizeof(float), stream);
  k0_prep<<<1028, 256, 0, stream>>>(ic, oc, cc, Bt, c2x, bf1, bf3, bf3l);
  k1_insweep<<<5120, 256, 0, stream>>>(x, c2x, bf1, S);
  k2_gemm<<<3200, 256, 0, stream>>>(Bt, S, U2a, U2b);
  k3_outsweep<<<5120, 256, 0, stream>>>(U2a, U2b, bf3, bf3l, bias, out);
}